// Round 3
// baseline (1658.656 us; speedup 1.0000x reference)
//
#include <hip/hip_runtime.h>
#include <math.h>

#define N 50000
#define E 600000
#define EPB 16     // edges per pass
#define NG 16      // dst nodes per block (group)
#define LDK 104    // padded K stride (bf16 elems)

typedef __attribute__((ext_vector_type(8))) short short8;
typedef __attribute__((ext_vector_type(4))) float float4v;

__device__ __forceinline__ float silu_f(float x) { return x / (1.f + __expf(-x)); }
__device__ __forceinline__ float sigm_f(float x) { return 1.f / (1.f + __expf(-x)); }
__device__ __forceinline__ unsigned short f2bf(float f) {
  unsigned u = __float_as_uint(f);
  u += 0x7fff + ((u >> 16) & 1);   // RNE
  return (unsigned short)(u >> 16);
}

// ---------------- CSR build ----------------
__global__ void k_hist(const int* __restrict__ eidx, int* __restrict__ counts) {
  int e = blockIdx.x * 256 + threadIdx.x;
  if (e < E) atomicAdd(&counts[eidx[E + e]], 1);
}

__global__ __launch_bounds__(1024)
void k_scan(const int* __restrict__ counts, int* __restrict__ row_ptr) {
  __shared__ int ssum[1024];
  const int t = threadIdx.x;
  const int CH = 49;                       // 1024*49 >= 50000
  int lo = t * CH, hi = min(lo + CH, N);
  int s = 0;
  for (int i = lo; i < hi; i++) s += counts[i];
  ssum[t] = s;
  __syncthreads();
  for (int off = 1; off < 1024; off <<= 1) {
    int v = (t >= off) ? ssum[t - off] : 0;
    __syncthreads();
    ssum[t] += v;
    __syncthreads();
  }
  int run = (t == 0) ? 0 : ssum[t - 1];
  for (int i = lo; i < hi; i++) { row_ptr[i] = run; run += counts[i]; }
  if (t == 1023) row_ptr[N] = ssum[1023];
}

__global__ void k_scatter(const int* __restrict__ eidx, const int* __restrict__ row_ptr,
                          int* __restrict__ woff, int* __restrict__ perm) {
  int e = blockIdx.x * 256 + threadIdx.x;
  if (e < E) {
    int d = eidx[E + e];
    int p = atomicAdd(&woff[d], 1);
    perm[row_ptr[d] + p] = e;
  }
}

// ---------------- Kernel A: s1 = node_s@W1s/8 ; v1 = node_v x W1v /sqrt(32) ----------------
__global__ __launch_bounds__(256, 4)
void k_lin1(const float* __restrict__ node_s, const float* __restrict__ node_v,
            const float* __restrict__ W1s, const float* __restrict__ W1v,
            float* __restrict__ s1, float* __restrict__ v1) {
  __shared__ float w1s[64 * 64];
  __shared__ float w1v[32 * 32];
  for (int i = threadIdx.x; i < 64 * 64; i += 256) w1s[i] = W1s[i];
  for (int i = threadIdx.x; i < 32 * 32; i += 256) w1v[i] = W1v[i];
  __syncthreads();
  const float is_ns = 0.125f;
  const float is_nv = 0.17677669529663689f;
  int gtid = blockIdx.x * 256 + threadIdx.x;
  int stride = gridDim.x * 256;
  for (int i = gtid; i < N * 160; i += stride) {
    int n = i / 160, ch = i % 160;
    if (ch < 64) {
      const float* row = node_s + n * 64;
      float acc = 0.f;
#pragma unroll
      for (int u = 0; u < 64; u++) acc += row[u] * w1s[u * 64 + ch];
      s1[n * 64 + ch] = acc * is_ns;
    } else {
      int p = ch - 64, v = p / 3, c = p % 3;
      const float* row = node_v + n * 96;
      float acc = 0.f;
#pragma unroll
      for (int u = 0; u < 32; u++) acc += row[u * 3 + c] * w1v[u * 32 + v];
      v1[n * 96 + p] = acc * is_nv;
    }
  }
}

// ---------------- Kernel B: dst-grouped message+aggregate (no global atomics) ----------------
__global__ __launch_bounds__(256, 4)
void k_msg(const float* __restrict__ s1, const float* __restrict__ v1,
           const float* __restrict__ emb, const float* __restrict__ sh0g,
           const float* __restrict__ sh1g, const int* __restrict__ eidx,
           const float* __restrict__ Wm1, const float* __restrict__ Wm2,
           const float* __restrict__ W2s, const float* __restrict__ W2v,
           const int* __restrict__ row_ptr, const int* __restrict__ perm,
           float* __restrict__ aggs, float* __restrict__ aggv) {
  __shared__ float wm2t[192 * 8];            // Wm2T[col][h]
  __shared__ float wm1s[64];
  __shared__ unsigned short tps[EPB * LDK];       // [e][k] bf16
  __shared__ unsigned short tpv[EPB * 3 * LDK];   // [(e*3+c)][k] bf16
  __shared__ float gat[EPB][32];
  __shared__ float hb[EPB][8];
  __shared__ float sh1b[EPB][4];
  __shared__ float sh0b[EPB];
  __shared__ int ssrc[EPB];
  __shared__ int srank[EPB];
  __shared__ float accS[NG][64];
  __shared__ float accV[NG][96];

  const int t = threadIdx.x;
  const int wave = t >> 6, lane = t & 63;
  const int lm = lane & 15, quad = lane >> 4;
  const float isq96 = 0.10206207261596575f;

  // ---- one-time staging: small MLP weights to LDS, W2 fragments to registers ----
  for (int i = t; i < 192 * 8; i += 256) {
    int h = i / 192, c = i % 192;
    wm2t[c * 8 + h] = Wm2[i];
  }
  if (t < 64) wm1s[t] = Wm1[t];

  // GEMM1 B frags: wave handles nt = wave (+4 for waves 0,1)
  short8 b1[2][3];
#pragma unroll
  for (int t2 = 0; t2 < 2; t2++) {
    const int nt = wave + t2 * 4;
    if (nt < 6) {
#pragma unroll
      for (int kk = 0; kk < 3; kk++) {
        unsigned short tmp[8];
#pragma unroll
        for (int i = 0; i < 8; i++)
          tmp[i] = f2bf(W2s[(kk * 32 + quad * 8 + i) * 96 + nt * 16 + lm]);
        b1[t2][kk] = *(short8*)tmp;
      }
    }
  }
  // GEMM2 B frags: wave's nt2 = wave&1
  short8 b2[3];
  {
    const int nt2 = wave & 1;
#pragma unroll
    for (int kk = 0; kk < 3; kk++) {
      unsigned short tmp[8];
#pragma unroll
      for (int i = 0; i < 8; i++)
        tmp[i] = f2bf(W2v[(kk * 32 + quad * 8 + i) * 32 + nt2 * 16 + lm]);
      b2[kk] = *(short8*)tmp;
    }
  }

  const int g = blockIdx.x;
  const int nbase = g * NG;
  const int e_start = row_ptr[nbase];
  const int e_end = row_ptr[nbase + NG];

  for (int i = t; i < NG * 64; i += 256) ((float*)accS)[i] = 0.f;
  for (int i = t; i < NG * 96; i += 256) ((float*)accV)[i] = 0.f;
  __syncthreads();

  const int npass = (e_end - e_start + EPB - 1) / EPB;
  for (int p = 0; p < npass; p++) {
    const int ebase = e_start + p * EPB;
    // ---- phase A: stage edge meta + radial MLP (disjoint thread sets) ----
    if (t < EPB) {
      const int idx = ebase + t;
      int eid, rank;
      if (idx < e_end) { eid = perm[idx]; rank = eidx[E + eid] - nbase; }
      else { eid = perm[e_start]; rank = -1; }
      ssrc[t] = eidx[eid];
      srank[t] = rank;
      sh0b[t] = sh0g[eid];
    } else if (t >= 64 && t < 64 + EPB * 3) {
      const int i = t - 64, el = i / 3, c = i - el * 3;
      const int idx = ebase + el;
      const int eid = perm[(idx < e_end) ? idx : e_start];
      sh1b[el][c] = sh1g[eid * 3 + c];
    } else if (t >= 128) {
      const int i = t - 128, el = i >> 3, sub = i & 7;
      const int idx = ebase + el;
      const int eid = perm[(idx < e_end) ? idx : e_start];
      float acc = 0.f;
#pragma unroll
      for (int r = 0; r < 8; r++) acc += emb[eid * 8 + r] * wm1s[r * 8 + sub];
      hb[el][sub] = silu_f(acc);
    }
    __syncthreads();
    // ---- phase B: build TPS / TPV (bf16) ----
    {
      const int el = t >> 4, sub = t & 15;
      const int src = ssrc[el];
      const float s0v = sh0b[el];
      const float x0 = sh1b[el][0], x1 = sh1b[el][1], x2 = sh1b[el][2];
      float hr[8];
#pragma unroll
      for (int h = 0; h < 8; h++) hr[h] = hb[el][h];
      const float4v ss = *(const float4v*)&s1[src * 64 + sub * 4];
      unsigned short tsv[4], tvv[3][4];
#pragma unroll
      for (int i = 0; i < 4; i++) {
        const int u = sub * 4 + i;
        float w0a = 0.f, w1a = 0.f;
#pragma unroll
        for (int h = 0; h < 8; h++) {
          w0a += hr[h] * wm2t[u * 8 + h];
          w1a += hr[h] * wm2t[(64 + u) * 8 + h];
        }
        const float ssu = ss[i];
        tsv[i] = f2bf(w0a * ssu * s0v);
        const float base = w1a * ssu;
        tvv[0][i] = f2bf(base * x0);
        tvv[1][i] = f2bf(base * x1);
        tvv[2][i] = f2bf(base * x2);
      }
      *(uint2*)&tps[el * LDK + sub * 4] = *(uint2*)tsv;
#pragma unroll
      for (int c = 0; c < 3; c++)
        *(uint2*)&tpv[(el * 3 + c) * LDK + sub * 4] = *(uint2*)tvv[c];
      const float2* vp = (const float2*)&v1[src * 96 + sub * 6];
      const float2 va = vp[0], vb = vp[1], vc = vp[2];
      const float v6[6] = {va.x, va.y, vb.x, vb.y, vc.x, vc.y};
      unsigned short ts2[2], tv2[3][2];
#pragma unroll
      for (int i2 = 0; i2 < 2; i2++) {
        const int u2 = sub * 2 + i2;
        float w1b = 0.f, w0b = 0.f;
#pragma unroll
        for (int h = 0; h < 8; h++) {
          w1b += hr[h] * wm2t[(128 + u2) * 8 + h];
          w0b += hr[h] * wm2t[(160 + u2) * 8 + h];
        }
        const float vx = v6[i2 * 3 + 0], vy = v6[i2 * 3 + 1], vz = v6[i2 * 3 + 2];
        ts2[i2] = f2bf(w0b * (vx * x0 + vy * x1 + vz * x2));
        tv2[0][i2] = f2bf(w1b * vx * s0v);
        tv2[1][i2] = f2bf(w1b * vy * s0v);
        tv2[2][i2] = f2bf(w1b * vz * s0v);
      }
      *(unsigned*)&tps[el * LDK + 64 + sub * 2] = *(unsigned*)ts2;
#pragma unroll
      for (int c = 0; c < 3; c++)
        *(unsigned*)&tpv[(el * 3 + c) * LDK + 64 + sub * 2] = *(unsigned*)tv2[c];
    }
    __syncthreads();
    // ---- GEMM1: m_s[16][96] ; silu -> LDS acc, sigmoid -> gates ----
    {
      short8 afr[3];
#pragma unroll
      for (int kk = 0; kk < 3; kk++)
        afr[kk] = *(const short8*)&tps[lm * LDK + kk * 32 + quad * 8];
#pragma unroll
      for (int t2 = 0; t2 < 2; t2++) {
        const int nt = wave + t2 * 4;
        if (nt < 6) {
          float4v acc = {0.f, 0.f, 0.f, 0.f};
#pragma unroll
          for (int kk = 0; kk < 3; kk++)
            acc = __builtin_amdgcn_mfma_f32_16x16x32_bf16(afr[kk], b1[t2][kk], acc, 0, 0, 0);
          const int j = nt * 16 + lm;
#pragma unroll
          for (int reg = 0; reg < 4; reg++) {
            const int e = quad * 4 + reg;
            const float val = acc[reg] * isq96;
            if (j < 64) {
              const int r = srank[e];
              if (r >= 0) atomicAdd(&accS[r][j], silu_f(val));
            } else {
              gat[e][j - 64] = sigm_f(val);
            }
          }
        }
      }
    }
    __syncthreads();
    // ---- GEMM2: m_v[48][32] ; gate -> LDS acc ----
#pragma unroll
    for (int t2 = 0; t2 < 2; t2++) {
      const int tile = wave + t2 * 4;
      if (tile < 6) {
        const int mt = tile >> 1;
        float4v acc = {0.f, 0.f, 0.f, 0.f};
#pragma unroll
        for (int kk = 0; kk < 3; kk++) {
          short8 a = *(const short8*)&tpv[(mt * 16 + lm) * LDK + kk * 32 + quad * 8];
          acc = __builtin_amdgcn_mfma_f32_16x16x32_bf16(a, b2[kk], acc, 0, 0, 0);
        }
        const int v = (wave & 1) * 16 + lm;
#pragma unroll
        for (int reg = 0; reg < 4; reg++) {
          const int r = mt * 16 + quad * 4 + reg;
          const int e = (r * 171) >> 9, c = r - 3 * e;
          const int rk = srank[e];
          if (rk >= 0) atomicAdd(&accV[rk][v * 3 + c], acc[reg] * isq96 * gat[e][v]);
        }
      }
    }
    __syncthreads();
  }
  // ---- final: plain coalesced stores of this group's agg rows ----
  for (int i = t; i < NG * 64; i += 256) {
    const int nl = i >> 6, u = i & 63;
    aggs[(size_t)(nbase + nl) * 64 + u] = accS[nl][u];
  }
  for (int i = t; i < NG * 96; i += 256) {
    const int nl = i / 96, r = i - nl * 96;
    aggv[(size_t)(nbase + nl) * 96 + r] = accV[nl][r];
  }
}

// ---------------- Kernel C1: f_s = (agg_s*d0)@W3s/8 + sc_s/32 ; write out_s + gates ----------------
#define C1_NT 32
__global__ __launch_bounds__(256, 2)
void k_c1(const float* __restrict__ node_s, const float* __restrict__ attrs,
          const float* __restrict__ aggs, const float* __restrict__ Wt0,
          const float* __restrict__ W3s, const float* __restrict__ Wsc0,
          float* __restrict__ out, float* __restrict__ gates) {
  __shared__ float wch[6144];
  __shared__ float s_row[C1_NT][64];
  __shared__ float attr[C1_NT][16];
  __shared__ float t0[C1_NT][64];
  const int t = threadIdx.x;
  const int jt = t & 31;
  const int nt = t >> 5;
  const int npass = (N + C1_NT - 1) / C1_NT;
  for (int pass = blockIdx.x; pass < npass; pass += gridDim.x) {
    const int nbase = pass * C1_NT;
    __syncthreads();
    for (int i = t; i < C1_NT * 64; i += 256) {
      int nl = i >> 6, u = i & 63, n = nbase + nl;
      s_row[nl][u] = (n < N) ? node_s[n * 64 + u] : 0.f;
      t0[nl][u]   = (n < N) ? aggs[n * 64 + u] : 0.f;
    }
    for (int i = t; i < C1_NT * 16; i += 256) {
      int nl = i >> 4, a = i & 15, n = nbase + nl;
      attr[nl][a] = (n < N) ? attrs[n * 16 + a] : 0.f;
    }
    __syncthreads();
    for (int i = t; i < C1_NT * 64; i += 256) {
      int nl = i >> 6, u = i & 63;
      float d0 = 0.f;
#pragma unroll
      for (int a = 0; a < 16; a++) d0 += attr[nl][a] * Wt0[u * 16 + a];
      t0[nl][u] *= d0 * 0.07216878364870322f;
    }
    float acc[4][3] = {};
    for (int chunk = 0; chunk < 16; chunk++) {
      __syncthreads();
      for (int i = t; i < 6144; i += 256) wch[i] = Wsc0[chunk * 6144 + i];
      __syncthreads();
#pragma unroll
      for (int uu = 0; uu < 4; uu++) {
        const int u = chunk * 4 + uu;
        float s4[4];
#pragma unroll
        for (int nl = 0; nl < 4; nl++) s4[nl] = s_row[nt + nl * 8][u];
#pragma unroll
        for (int a = 0; a < 16; a++) {
          const int kl = uu * 16 + a;
          const float w0 = wch[kl * 96 + jt];
          const float w1 = wch[kl * 96 + jt + 32];
          const float w2 = wch[kl * 96 + jt + 64];
#pragma unroll
          for (int nl = 0; nl < 4; nl++) {
            const float z = s4[nl] * attr[nt + nl * 8][a];
            acc[nl][0] += z * w0; acc[nl][1] += z * w1; acc[nl][2] += z * w2;
          }
        }
      }
    }
    __syncthreads();
    for (int i = t; i < 6144; i += 256) wch[i] = W3s[i];
    __syncthreads();
    float facc[4][3] = {};
#pragma unroll 4
    for (int u = 0; u < 64; u++) {
      const float w0 = wch[u * 96 + jt];
      const float w1 = wch[u * 96 + jt + 32];
      const float w2 = wch[u * 96 + jt + 64];
#pragma unroll
      for (int nl = 0; nl < 4; nl++) {
        const float tv = t0[nt + nl * 8][u];
        facc[nl][0] += tv * w0; facc[nl][1] += tv * w1; facc[nl][2] += tv * w2;
      }
    }
#pragma unroll
    for (int nl = 0; nl < 4; nl++) {
      const int n = nbase + nt + nl * 8;
      if (n >= N) continue;
#pragma unroll
      for (int jo = 0; jo < 3; jo++) {
        const int j = jt + jo * 32;
        const float f = facc[nl][jo] * 0.125f + acc[nl][jo] * 0.03125f;
        if (j < 64) out[n * 160 + j] = silu_f(f);
        else        gates[n * 32 + (j - 64)] = sigm_f(f);
      }
    }
  }
}

// ---------------- Kernel C2: f_v = (agg_v*d1)@W3v/sqrt(32) + sc_v/sqrt(512), * gate ----------------
__global__ __launch_bounds__(256, 2)
void k_c2(const float* __restrict__ node_v, const float* __restrict__ attrs,
          const float* __restrict__ aggv, const float* __restrict__ Wt1,
          const float* __restrict__ W3v, const float* __restrict__ Wsc1,
          const float* __restrict__ gates, float* __restrict__ out) {
  __shared__ float wsc[4096];
  __shared__ float w3v[1024];
  __shared__ float nv[8][96];
  __shared__ float t1[8][96];
  __shared__ float attr[8][16];
  const int t = threadIdx.x;
  const int w = t & 31, nl = t >> 5;
  for (int i = t; i < 1024; i += 256) w3v[i] = W3v[i];
  for (int pass = blockIdx.x; pass < N / 8; pass += gridDim.x) {
    const int nbase = pass * 8;
    __syncthreads();
    for (int i = t; i < 8 * 96; i += 256) {
      int n = i / 96, r = i % 96;
      nv[n][r] = node_v[(nbase + n) * 96 + r];
      t1[n][r] = aggv[(nbase + n) * 96 + r];
    }
    if (t < 128) attr[t >> 4][t & 15] = attrs[nbase * 16 + t];
    __syncthreads();
    {
      const int u = w;
      float d1 = 0.f;
#pragma unroll
      for (int a = 0; a < 16; a++) d1 += attr[nl][a] * Wt1[u * 16 + a];
      d1 *= 0.07216878364870322f;
      t1[nl][u * 3 + 0] *= d1; t1[nl][u * 3 + 1] *= d1; t1[nl][u * 3 + 2] *= d1;
    }
    float scv0 = 0.f, scv1 = 0.f, scv2 = 0.f;
    for (int cu = 0; cu < 4; cu++) {
      __syncthreads();
      for (int i = t; i < 4096; i += 256) wsc[i] = Wsc1[cu * 4096 + i];
      __syncthreads();
#pragma unroll
      for (int u8 = 0; u8 < 8; u8++) {
        const int u = cu * 8 + u8;
        float g = 0.f;
#pragma unroll
        for (int a = 0; a < 16; a++) g += attr[nl][a] * wsc[(u8 * 16 + a) * 32 + w];
        scv0 += nv[nl][u * 3 + 0] * g;
        scv1 += nv[nl][u * 3 + 1] * g;
        scv2 += nv[nl][u * 3 + 2] * g;
      }
    }
    float fv0 = 0.f, fv1 = 0.f, fv2 = 0.f;
#pragma unroll 8
    for (int u = 0; u < 32; u++) {
      const float wv = w3v[u * 32 + w];
      fv0 += t1[nl][u * 3 + 0] * wv;
      fv1 += t1[nl][u * 3 + 1] * wv;
      fv2 += t1[nl][u * 3 + 2] * wv;
    }
    const int n = nbase + nl;
    const float gate = gates[n * 32 + w];
    const float is32 = 0.17677669529663689f;
    const float is512 = 0.044194173824159216f;
    out[n * 160 + 64 + w * 3 + 0] = (fv0 * is32 + scv0 * is512) * gate;
    out[n * 160 + 64 + w * 3 + 1] = (fv1 * is32 + scv1 * is512) * gate;
    out[n * 160 + 64 + w * 3 + 2] = (fv2 * is32 + scv2 * is512) * gate;
  }
}

extern "C" void kernel_launch(void* const* d_in, const int* in_sizes, int n_in,
                              void* d_out, int out_size, void* d_ws, size_t ws_size,
                              hipStream_t stream) {
  const float* node_s = (const float*)d_in[0];
  const float* node_v = (const float*)d_in[1];
  const float* attrs  = (const float*)d_in[2];
  const float* emb    = (const float*)d_in[3];
  const float* sh0    = (const float*)d_in[4];
  const float* sh1    = (const float*)d_in[5];
  const int*   eidx   = (const int*)d_in[6];
  const float* W1s    = (const float*)d_in[7];
  const float* W1v    = (const float*)d_in[8];
  const float* Wm1    = (const float*)d_in[9];
  const float* Wm2    = (const float*)d_in[10];
  const float* W2s    = (const float*)d_in[11];
  const float* W2v    = (const float*)d_in[12];
  const float* Wt0    = (const float*)d_in[13];
  const float* Wt1    = (const float*)d_in[14];
  const float* W3s    = (const float*)d_in[15];
  const float* W3v    = (const float*)d_in[16];
  const float* Wsc0   = (const float*)d_in[17];
  const float* Wsc1   = (const float*)d_in[18];

  float* ws   = (float*)d_ws;
  float* s1   = ws;                         // N*64
  float* v1   = ws + (size_t)N * 64;        // N*96
  float* aggs = ws + (size_t)N * 160;       // N*64
  float* aggv = ws + (size_t)N * 224;       // N*96
  float* gts  = ws + (size_t)N * 320;       // N*32
  int* ibase  = (int*)(ws + (size_t)N * 352);
  int* counts = ibase;                      // N
  int* woff   = ibase + N;                  // N
  int* rowp   = ibase + 2 * N;              // N+1
  int* perm   = ibase + 3 * N + 1;          // E

  hipMemsetAsync(counts, 0, (size_t)2 * N * sizeof(int), stream);
  k_hist<<<(E + 255) / 256, 256, 0, stream>>>(eidx, counts);
  k_scan<<<1, 1024, 0, stream>>>(counts, rowp);
  k_scatter<<<(E + 255) / 256, 256, 0, stream>>>(eidx, rowp, woff, perm);
  k_lin1<<<1024, 256, 0, stream>>>(node_s, node_v, W1s, W1v, s1, v1);
  k_msg<<<N / NG, 256, 0, stream>>>(s1, v1, emb, sh0, sh1, eidx, Wm1, Wm2, W2s, W2v,
                                    rowp, perm, aggs, aggv);
  k_c1<<<512, 256, 0, stream>>>(node_s, attrs, aggs, Wt0, W3s, Wsc0, (float*)d_out, gts);
  k_c2<<<512, 256, 0, stream>>>(node_v, attrs, aggv, Wt1, W3v, Wsc1, gts, (float*)d_out);
}

// Round 4
// 906.041 us; speedup vs baseline: 1.8307x; 1.8307x over previous
//
#include <hip/hip_runtime.h>
#include <math.h>

#define N 50000
#define E 600000
#define EPB 16     // edges per pass
#define LDK 104    // padded K stride (bf16 elems) for tp tiles

typedef __attribute__((ext_vector_type(8))) short short8;
typedef __attribute__((ext_vector_type(4))) float float4v;

__device__ __forceinline__ float silu_f(float x) { return x / (1.f + __expf(-x)); }
__device__ __forceinline__ float sigm_f(float x) { return 1.f / (1.f + __expf(-x)); }
__device__ __forceinline__ unsigned short f2bf(float f) {
  unsigned u = __float_as_uint(f);
  u += 0x7fff + ((u >> 16) & 1);   // RNE
  return (unsigned short)(u >> 16);
}
__device__ __forceinline__ float bf2f(unsigned short u) {
  return __uint_as_float(((unsigned)u) << 16);
}

// ---------------- CSR build ----------------
__global__ void k_hist(const int* __restrict__ eidx, int* __restrict__ counts) {
  int e = blockIdx.x * 256 + threadIdx.x;
  if (e < E) atomicAdd(&counts[eidx[E + e]], 1);
}

__global__ __launch_bounds__(1024)
void k_scan(const int* __restrict__ counts, int* __restrict__ row_ptr) {
  __shared__ int ssum[1024];
  const int t = threadIdx.x;
  const int CH = 49;
  int lo = t * CH, hi = min(lo + CH, N);
  int s = 0;
  for (int i = lo; i < hi; i++) s += counts[i];
  ssum[t] = s;
  __syncthreads();
  for (int off = 1; off < 1024; off <<= 1) {
    int v = (t >= off) ? ssum[t - off] : 0;
    __syncthreads();
    ssum[t] += v;
    __syncthreads();
  }
  int run = (t == 0) ? 0 : ssum[t - 1];
  for (int i = lo; i < hi; i++) { row_ptr[i] = run; run += counts[i]; }
  if (t == 1023) row_ptr[N] = ssum[1023];
}

__global__ void k_scatter(const int* __restrict__ eidx, const int* __restrict__ row_ptr,
                          int* __restrict__ woff, int* __restrict__ pos) {
  int e = blockIdx.x * 256 + threadIdx.x;
  if (e < E) {
    int d = eidx[E + e];
    int p = atomicAdd(&woff[d], 1);
    pos[e] = row_ptr[d] + p;
  }
}

// ---------------- weight prep: bf16 transposed B matrices for k_c1/k_c2 ----------------
__global__ void k_prep(const float* __restrict__ Wsc0, const float* __restrict__ W3s,
                       const float* __restrict__ Wsc1, const float* __restrict__ W3v,
                       unsigned short* __restrict__ BT, unsigned short* __restrict__ B2T) {
  int i = blockIdx.x * 256 + threadIdx.x;
  if (i < 96 * 1088) {
    int j = i / 1088, k = i % 1088;
    float v;
    if (k < 1024) v = Wsc0[(size_t)k * 96 + j] * 0.03125f;          // 1/sqrt(1024)
    else          v = W3s[(size_t)(k - 1024) * 96 + j] * 0.125f;    // 1/sqrt(64)
    BT[i] = f2bf(v);
  } else {
    int i2 = i - 96 * 1088;
    if (i2 < 32 * 576) {
      int w = i2 / 576, k = i2 % 576;
      float v = 0.f;
      if (k < 512)      v = Wsc1[(size_t)k * 32 + w] * 0.04419417382415922f;  // 1/sqrt(512)
      else if (k < 544) v = W3v[(size_t)(k - 512) * 32 + w] * 0.17677669529663689f; // 1/sqrt(32)
      B2T[i2] = f2bf(v);
    }
  }
}

// ---------------- Kernel A: s1 = node_s@W1s/8 ; v1 = node_v x W1v /sqrt(32) ----------------
__global__ __launch_bounds__(256, 4)
void k_lin1(const float* __restrict__ node_s, const float* __restrict__ node_v,
            const float* __restrict__ W1s, const float* __restrict__ W1v,
            float* __restrict__ s1, float* __restrict__ v1) {
  __shared__ float w1s[64 * 64];
  __shared__ float w1v[32 * 32];
  for (int i = threadIdx.x; i < 64 * 64; i += 256) w1s[i] = W1s[i];
  for (int i = threadIdx.x; i < 32 * 32; i += 256) w1v[i] = W1v[i];
  __syncthreads();
  const float is_ns = 0.125f;
  const float is_nv = 0.17677669529663689f;
  int gtid = blockIdx.x * 256 + threadIdx.x;
  int stride = gridDim.x * 256;
  for (int i = gtid; i < N * 160; i += stride) {
    int n = i / 160, ch = i % 160;
    if (ch < 64) {
      const float* row = node_s + n * 64;
      float acc = 0.f;
#pragma unroll
      for (int u = 0; u < 64; u++) acc += row[u] * w1s[u * 64 + ch];
      s1[n * 64 + ch] = acc * is_ns;
    } else {
      int p = ch - 64, v = p / 3, c = p % 3;
      const float* row = node_v + n * 96;
      float acc = 0.f;
#pragma unroll
      for (int u = 0; u < 32; u++) acc += row[u * 3 + c] * w1v[u * 32 + v];
      v1[n * 96 + p] = acc * is_nv;
    }
  }
}

// ---------------- Kernel B: streaming per-edge message via MFMA ----------------
// STORE=1: write bf16 messages at CSR position pos[e] (no atomics)
// STORE=0: fallback, atomicAdd into aggs/aggv (round-2 proven path)
template<int STORE>
__global__ __launch_bounds__(256, 4)
void k_msg(const float* __restrict__ s1, const float* __restrict__ v1,
           const float* __restrict__ emb, const float* __restrict__ sh0g,
           const float* __restrict__ sh1g, const int* __restrict__ eidx,
           const float* __restrict__ Wm1, const float* __restrict__ Wm2,
           const float* __restrict__ W2s, const float* __restrict__ W2v,
           const int* __restrict__ pos,
           float* __restrict__ aggs, float* __restrict__ aggv,
           unsigned short* __restrict__ msgS, unsigned short* __restrict__ msgV) {
  __shared__ float wm2t[192 * 8];
  __shared__ float wm1s[64];
  __shared__ unsigned short tps[EPB * LDK];
  __shared__ unsigned short tpv[EPB * 3 * LDK];
  __shared__ float gat[EPB][32];
  __shared__ float hb[EPB][8];
  __shared__ float sh1b[EPB][4];
  __shared__ float sh0b[EPB];
  __shared__ int ssrc[EPB];
  __shared__ int smeta[EPB];     // pos (STORE) or dst (atomic)

  const int t = threadIdx.x;
  const int wave = t >> 6, lane = t & 63;
  const int lm = lane & 15, quad = lane >> 4;
  const float isq96 = 0.10206207261596575f;

  for (int i = t; i < 192 * 8; i += 256) {
    int h = i / 192, c = i % 192;
    wm2t[c * 8 + h] = Wm2[i];
  }
  if (t < 64) wm1s[t] = Wm1[t];

  // W2 B-fragments in registers
  short8 b1[2][3];
#pragma unroll
  for (int t2 = 0; t2 < 2; t2++) {
    const int nt = wave + t2 * 4;
    if (nt < 6) {
#pragma unroll
      for (int kk = 0; kk < 3; kk++) {
        unsigned short tmp[8];
#pragma unroll
        for (int i = 0; i < 8; i++)
          tmp[i] = f2bf(W2s[(kk * 32 + quad * 8 + i) * 96 + nt * 16 + lm]);
        b1[t2][kk] = *(short8*)tmp;
      }
    }
  }
  short8 b2[3];
  {
    const int nt2 = wave & 1;
#pragma unroll
    for (int kk = 0; kk < 3; kk++) {
      unsigned short tmp[8];
#pragma unroll
      for (int i = 0; i < 8; i++)
        tmp[i] = f2bf(W2v[(kk * 32 + quad * 8 + i) * 32 + nt2 * 16 + lm]);
      b2[kk] = *(short8*)tmp;
    }
  }

  for (int pass = blockIdx.x; pass < E / EPB; pass += gridDim.x) {
    const int ebase = pass * EPB;
    __syncthreads();
    // ---- stage per-edge data (coalesced, original edge order) ----
    if (t < EPB) {
      ssrc[t] = eidx[ebase + t];
      smeta[t] = STORE ? pos[ebase + t] : eidx[E + ebase + t];
      sh0b[t] = sh0g[ebase + t];
    } else if (t >= 64 && t < 64 + EPB * 3) {
      int i = t - 64;
      sh1b[i / 3][i % 3] = sh1g[ebase * 3 + i];
    } else if (t >= 128) {
      int i = t - 128, el = i >> 3, sub = i & 7;
      float acc = 0.f;
#pragma unroll
      for (int r = 0; r < 8; r++) acc += emb[(ebase + el) * 8 + r] * wm1s[r * 8 + sub];
      hb[el][sub] = silu_f(acc);
    }
    __syncthreads();
    // ---- build TPS / TPV (bf16) ----
    {
      const int el = t >> 4, sub = t & 15;
      const int src = ssrc[el];
      const float s0v = sh0b[el];
      const float x0 = sh1b[el][0], x1 = sh1b[el][1], x2 = sh1b[el][2];
      float hr[8];
#pragma unroll
      for (int h = 0; h < 8; h++) hr[h] = hb[el][h];
      const float4v ss = *(const float4v*)&s1[(size_t)src * 64 + sub * 4];
      unsigned short tsv[4], tvv[3][4];
#pragma unroll
      for (int i = 0; i < 4; i++) {
        const int u = sub * 4 + i;
        float w0a = 0.f, w1a = 0.f;
#pragma unroll
        for (int h = 0; h < 8; h++) {
          w0a += hr[h] * wm2t[u * 8 + h];
          w1a += hr[h] * wm2t[(64 + u) * 8 + h];
        }
        const float ssu = ss[i];
        tsv[i] = f2bf(w0a * ssu * s0v);
        const float base = w1a * ssu;
        tvv[0][i] = f2bf(base * x0);
        tvv[1][i] = f2bf(base * x1);
        tvv[2][i] = f2bf(base * x2);
      }
      *(uint2*)&tps[el * LDK + sub * 4] = *(uint2*)tsv;
#pragma unroll
      for (int c = 0; c < 3; c++)
        *(uint2*)&tpv[(el * 3 + c) * LDK + sub * 4] = *(uint2*)tvv[c];
      const float2* vp = (const float2*)&v1[(size_t)src * 96 + sub * 6];
      const float2 va = vp[0], vb = vp[1], vc = vp[2];
      const float v6[6] = {va.x, va.y, vb.x, vb.y, vc.x, vc.y};
      unsigned short ts2[2], tv2[3][2];
#pragma unroll
      for (int i2 = 0; i2 < 2; i2++) {
        const int u2 = sub * 2 + i2;
        float w1b = 0.f, w0b = 0.f;
#pragma unroll
        for (int h = 0; h < 8; h++) {
          w1b += hr[h] * wm2t[(128 + u2) * 8 + h];
          w0b += hr[h] * wm2t[(160 + u2) * 8 + h];
        }
        const float vx = v6[i2 * 3 + 0], vy = v6[i2 * 3 + 1], vz = v6[i2 * 3 + 2];
        ts2[i2] = f2bf(w0b * (vx * x0 + vy * x1 + vz * x2));
        tv2[0][i2] = f2bf(w1b * vx * s0v);
        tv2[1][i2] = f2bf(w1b * vy * s0v);
        tv2[2][i2] = f2bf(w1b * vz * s0v);
      }
      *(unsigned*)&tps[el * LDK + 64 + sub * 2] = *(unsigned*)ts2;
#pragma unroll
      for (int c = 0; c < 3; c++)
        *(unsigned*)&tpv[(el * 3 + c) * LDK + 64 + sub * 2] = *(unsigned*)tv2[c];
    }
    __syncthreads();
    // ---- GEMM1: m_s[16][96] ----
    {
      short8 afr[3];
#pragma unroll
      for (int kk = 0; kk < 3; kk++)
        afr[kk] = *(const short8*)&tps[lm * LDK + kk * 32 + quad * 8];
#pragma unroll
      for (int t2 = 0; t2 < 2; t2++) {
        const int nt = wave + t2 * 4;
        if (nt < 6) {
          float4v acc = {0.f, 0.f, 0.f, 0.f};
#pragma unroll
          for (int kk = 0; kk < 3; kk++)
            acc = __builtin_amdgcn_mfma_f32_16x16x32_bf16(afr[kk], b1[t2][kk], acc, 0, 0, 0);
          const int j = nt * 16 + lm;
#pragma unroll
          for (int reg = 0; reg < 4; reg++) {
            const int e = quad * 4 + reg;
            const float val = acc[reg] * isq96;
            if (j < 64) {
              if (STORE) msgS[(size_t)smeta[e] * 64 + j] = f2bf(silu_f(val));
              else atomicAdd(&aggs[(size_t)smeta[e] * 64 + j], silu_f(val));
            } else {
              gat[e][j - 64] = sigm_f(val);
            }
          }
        }
      }
    }
    __syncthreads();
    // ---- GEMM2: m_v[48][32] ----
#pragma unroll
    for (int t2 = 0; t2 < 2; t2++) {
      const int tile = wave + t2 * 4;
      if (tile < 6) {
        const int mt = tile >> 1;
        float4v acc = {0.f, 0.f, 0.f, 0.f};
#pragma unroll
        for (int kk = 0; kk < 3; kk++) {
          short8 a = *(const short8*)&tpv[(mt * 16 + lm) * LDK + kk * 32 + quad * 8];
          acc = __builtin_amdgcn_mfma_f32_16x16x32_bf16(a, b2[kk], acc, 0, 0, 0);
        }
        const int v = (wave & 1) * 16 + lm;
#pragma unroll
        for (int reg = 0; reg < 4; reg++) {
          const int r = mt * 16 + quad * 4 + reg;
          const int e = (r * 171) >> 9, c = r - 3 * e;
          const float val = acc[reg] * isq96 * gat[e][v];
          if (STORE) msgV[(size_t)smeta[e] * 96 + v * 3 + c] = f2bf(val);
          else atomicAdd(&aggv[(size_t)smeta[e] * 96 + v * 3 + c], val);
        }
      }
    }
  }
}

// ---------------- Kernel B2: wave-per-node contiguous reduction ----------------
__global__ __launch_bounds__(256, 8)
void k_agg(const unsigned short* __restrict__ msgS, const unsigned short* __restrict__ msgV,
           const int* __restrict__ rowp, float* __restrict__ aggs, float* __restrict__ aggv) {
  const int wv = threadIdx.x >> 6, lane = threadIdx.x & 63;
  const int n = blockIdx.x * 4 + wv;
  const int lo = rowp[n], hi = rowp[n + 1];
  float sS = 0.f, v0 = 0.f, v1a = 0.f;
  for (int r = lo; r < hi; r++) {
    sS += bf2f(msgS[(size_t)r * 64 + lane]);
    v0 += bf2f(msgV[(size_t)r * 96 + lane]);
    if (lane < 32) v1a += bf2f(msgV[(size_t)r * 96 + 64 + lane]);
  }
  aggs[(size_t)n * 64 + lane] = sS;
  aggv[(size_t)n * 96 + lane] = v0;
  if (lane < 32) aggv[(size_t)n * 96 + 64 + lane] = v1a;
}

// ---------------- Kernel C1: MFMA GEMM  [32 nodes x 1088] @ BT^T -> 96 cols ----------------
__global__ __launch_bounds__(256, 4)
void k_c1(const float* __restrict__ node_s, const float* __restrict__ attrs,
          const float* __restrict__ aggs, const float* __restrict__ Wt0,
          const unsigned short* __restrict__ BT,
          float* __restrict__ out, float* __restrict__ gates) {
  __shared__ float s_row[32][64];
  __shared__ float attr[32][16];
  __shared__ float t0[32][64];
  __shared__ float wt0[1024];
  __shared__ unsigned short As[32 * 72];
  const int t = threadIdx.x;
  const int wave = t >> 6, lane = t & 63, lm = lane & 15, quad = lane >> 4;
  const int nbase = blockIdx.x * 32;

  for (int i = t; i < 1024; i += 256) wt0[i] = Wt0[i];
  for (int i = t; i < 2048; i += 256) {
    int nl = i >> 6, u = i & 63, n = nbase + nl;
    s_row[nl][u] = (n < N) ? node_s[(size_t)n * 64 + u] : 0.f;
    t0[nl][u]    = (n < N) ? aggs[(size_t)n * 64 + u] : 0.f;
  }
  for (int i = t; i < 512; i += 256) {
    int nl = i >> 4, a = i & 15, n = nbase + nl;
    attr[nl][a] = (n < N) ? attrs[(size_t)n * 16 + a] : 0.f;
  }
  __syncthreads();
  for (int i = t; i < 2048; i += 256) {
    int nl = i >> 6, u = i & 63;
    float d0 = 0.f;
#pragma unroll
    for (int a = 0; a < 16; a++) d0 += attr[nl][a] * wt0[u * 16 + a];
    t0[nl][u] *= d0 * 0.07216878364870322f;   // 1/(sqrt(16)*sqrt(12))
  }

  float4v acc[3] = {{0,0,0,0},{0,0,0,0},{0,0,0,0}};
  int mts[3], nts[3];
#pragma unroll
  for (int tt = 0; tt < 3; tt++) {
    const int tile = wave + tt * 4;    // 0..11 = mt*6+nt
    mts[tt] = tile / 6;
    nts[tt] = tile % 6;
  }

  for (int kc = 0; kc < 17; kc++) {
    __syncthreads();
    {
      const int row = t >> 3, c0 = (t & 7) * 8;
      unsigned short tmp[8];
      if (kc < 16) {
        const int u = kc * 4 + (c0 >> 4);
        const float sval = s_row[row][u];
        const int ab = c0 & 8;
#pragma unroll
        for (int i = 0; i < 8; i++) tmp[i] = f2bf(sval * attr[row][ab + i]);
      } else {
#pragma unroll
        for (int i = 0; i < 8; i++) tmp[i] = f2bf(t0[row][c0 + i]);
      }
      *(uint4*)&As[row * 72 + c0] = *(uint4*)tmp;
    }
    __syncthreads();
#pragma unroll
    for (int ks = 0; ks < 2; ks++) {
      short8 am0 = *(const short8*)&As[(lm) * 72 + ks * 32 + quad * 8];
      short8 am1 = *(const short8*)&As[(16 + lm) * 72 + ks * 32 + quad * 8];
#pragma unroll
      for (int tt = 0; tt < 3; tt++) {
        short8 b = *(const short8*)&BT[(size_t)(nts[tt] * 16 + lm) * 1088 + kc * 64 + ks * 32 + quad * 8];
        acc[tt] = __builtin_amdgcn_mfma_f32_16x16x32_bf16(mts[tt] ? am1 : am0, b, acc[tt], 0, 0, 0);
      }
    }
  }
#pragma unroll
  for (int tt = 0; tt < 3; tt++) {
    const int j = nts[tt] * 16 + lm;
#pragma unroll
    for (int reg = 0; reg < 4; reg++) {
      const int m = mts[tt] * 16 + quad * 4 + reg;
      const int n = nbase + m;
      if (n < N) {
        const float val = acc[tt][reg];
        if (j < 64) out[(size_t)n * 160 + j] = silu_f(val);
        else        gates[(size_t)n * 32 + (j - 64)] = sigm_f(val);
      }
    }
  }
}

// ---------------- Kernel C2: MFMA GEMM  [96 rows (32n x 3c) x 544] @ B2T^T -> 32 cols ----------------
__global__ __launch_bounds__(256, 3)
void k_c2(const float* __restrict__ node_v, const float* __restrict__ attrs,
          const float* __restrict__ aggv, const float* __restrict__ Wt1,
          const unsigned short* __restrict__ B2T, const float* __restrict__ gts,
          float* __restrict__ out) {
  __shared__ float nvs[32][96];
  __shared__ float t1s[32][96];
  __shared__ float attr[32][16];
  __shared__ float wt1[512];
  __shared__ unsigned short As2[96 * 72];
  const int t = threadIdx.x;
  const int wave = t >> 6, lane = t & 63, lm = lane & 15, quad = lane >> 4;
  const int nbase = blockIdx.x * 32;

  for (int i = t; i < 512; i += 256) wt1[i] = Wt1[i];
  for (int i = t; i < 32 * 96; i += 256) {
    int nl = i / 96, rr = i % 96, n = nbase + nl;
    nvs[nl][rr] = (n < N) ? node_v[(size_t)n * 96 + rr] : 0.f;
    t1s[nl][rr] = (n < N) ? aggv[(size_t)n * 96 + rr] : 0.f;
  }
  for (int i = t; i < 512; i += 256) {
    int nl = i >> 4, a = i & 15, n = nbase + nl;
    attr[nl][a] = (n < N) ? attrs[(size_t)n * 16 + a] : 0.f;
  }
  __syncthreads();
  for (int i = t; i < 1024; i += 256) {
    int nl = i >> 5, u = i & 31;
    float d1 = 0.f;
#pragma unroll
    for (int a = 0; a < 16; a++) d1 += attr[nl][a] * wt1[u * 16 + a];
    d1 *= 0.07216878364870322f;
    t1s[nl][u * 3 + 0] *= d1; t1s[nl][u * 3 + 1] *= d1; t1s[nl][u * 3 + 2] *= d1;
  }

  float4v acc[3] = {{0,0,0,0},{0,0,0,0},{0,0,0,0}};
  int mts[3], nts[3];
#pragma unroll
  for (int tt = 0; tt < 3; tt++) {
    const int tile = wave + tt * 4;   // 0..11 = mt*2+nt
    mts[tt] = tile >> 1;
    nts[tt] = tile & 1;
  }

  for (int kc = 0; kc < 9; kc++) {
    __syncthreads();
#pragma unroll
    for (int jj = 0; jj < 3; jj++) {
      const int job = t + jj * 256;
      const int row = job >> 3, c0 = (job & 7) * 8;
      const int nl = (row * 171) >> 9, c = row - 3 * nl;
      const int kbase = kc * 64 + c0;
      unsigned short tmp[8];
      if (kbase < 512) {
        const int u = kbase >> 4;
        const float vval = nvs[nl][u * 3 + c];
        const int ab = c0 & 8;
#pragma unroll
        for (int i = 0; i < 8; i++) tmp[i] = f2bf(vval * attr[nl][ab + i]);
      } else if (kbase < 544) {
        const int u2 = kbase - 512;
#pragma unroll
        for (int i = 0; i < 8; i++) tmp[i] = f2bf(t1s[nl][(u2 + i) * 3 + c]);
      } else {
#pragma unroll
        for (int i = 0; i < 8; i++) tmp[i] = 0;
      }
      *(uint4*)&As2[row * 72 + c0] = *(uint4*)tmp;
    }
    __syncthreads();
#pragma unroll
    for (int ks = 0; ks < 2; ks++) {
#pragma unroll
      for (int tt = 0; tt < 3; tt++) {
        short8 a = *(const short8*)&As2[(mts[tt] * 16 + lm) * 72 + ks * 32 + quad * 8];
        short8 b = *(const short8*)&B2T[(size_t)(nts[tt] * 16 + lm) * 576 + kc * 64 + ks * 32 + quad * 8];
        acc[tt] = __builtin_amdgcn_mfma_f32_16x16x32_bf16(a, b, acc[tt], 0, 0, 0);
      }
    }
  }
#pragma unroll
  for (int tt = 0; tt < 3; tt++) {
    const int w = nts[tt] * 16 + lm;
#pragma unroll
    for (int reg = 0; reg < 4; reg++) {
      const int row = mts[tt] * 16 + quad * 4 + reg;
      const int nl = (row * 171) >> 9, c = row - 3 * nl;
      const int n = nbase + nl;
      if (n < N)
        out[(size_t)n * 160 + 64 + w * 3 + c] = acc[tt][reg] * gts[(size_t)n * 32 + w];
    }
  }
}

extern "C" void kernel_launch(void* const* d_in, const int* in_sizes, int n_in,
                              void* d_out, int out_size, void* d_ws, size_t ws_size,
                              hipStream_t stream) {
  const float* node_s = (const float*)d_in[0];
  const float* node_v = (const float*)d_in[1];
  const float* attrs  = (const float*)d_in[2];
  const float* emb    = (const float*)d_in[3];
  const float* sh0    = (const float*)d_in[4];
  const float* sh1    = (const float*)d_in[5];
  const int*   eidx   = (const int*)d_in[6];
  const float* W1s    = (const float*)d_in[7];
  const float* W1v    = (const float*)d_in[8];
  const float* Wm1    = (const float*)d_in[9];
  const float* Wm2    = (const float*)d_in[10];
  const float* W2s    = (const float*)d_in[11];
  const float* W2v    = (const float*)d_in[12];
  const float* Wt0    = (const float*)d_in[13];
  const float* Wt1    = (const float*)d_in[14];
  const float* W3s    = (const float*)d_in[15];
  const float* W3v    = (const float*)d_in[16];
  const float* Wsc0   = (const float*)d_in[17];
  const float* Wsc1   = (const float*)d_in[18];

  char* p = (char*)d_ws;
  float* s1  = (float*)p;  p += (size_t)N * 64 * 4;
  float* v1f = (float*)p;  p += (size_t)N * 96 * 4;
  float* gts = (float*)p;  p += (size_t)N * 32 * 4;
  unsigned short* BT  = (unsigned short*)p;  p += (size_t)96 * 1088 * 2;
  unsigned short* B2T = (unsigned short*)p;  p += (size_t)32 * 576 * 2;
  char* pmode = p;
  size_t base = (size_t)(pmode - (char*)d_ws);
  size_t need_store = base + ((size_t)N + 1) * 4 + (size_t)N * 4 + (size_t)E * 4
                    + (size_t)E * 64 * 2 + (size_t)E * 96 * 2;
  const bool store = (ws_size >= need_store);

  k_prep<<<480, 256, 0, stream>>>(Wsc0, W3s, Wsc1, W3v, BT, B2T);
  k_lin1<<<1024, 256, 0, stream>>>(node_s, node_v, W1s, W1v, s1, v1f);

  if (store) {
    int* rowp = (int*)pmode;
    int* cnt  = rowp + (N + 1);
    int* pos  = cnt + N;
    unsigned short* msgS = (unsigned short*)(pos + E);
    unsigned short* msgV = msgS + (size_t)E * 64;
    hipMemsetAsync(cnt, 0, (size_t)N * 4, stream);
    k_hist<<<(E + 255) / 256, 256, 0, stream>>>(eidx, cnt);
    k_scan<<<1, 1024, 0, stream>>>(cnt, rowp);
    hipMemsetAsync(cnt, 0, (size_t)N * 4, stream);
    k_scatter<<<(E + 255) / 256, 256, 0, stream>>>(eidx, rowp, cnt, pos);
    k_msg<1><<<1536, 256, 0, stream>>>(s1, v1f, emb, sh0, sh1, eidx, Wm1, Wm2, W2s, W2v,
                                       pos, nullptr, nullptr, msgS, msgV);
    float* aggs = s1;    // s1/v1 dead after k_msg: alias
    float* aggv = v1f;
    k_agg<<<N / 4, 256, 0, stream>>>(msgS, msgV, rowp, aggs, aggv);
    k_c1<<<1563, 256, 0, stream>>>(node_s, attrs, aggs, Wt0, BT, (float*)d_out, gts);
    k_c2<<<1563, 256, 0, stream>>>(node_v, attrs, aggv, Wt1, B2T, gts, (float*)d_out);
  } else {
    float* aggs = (float*)pmode;
    float* aggv = aggs + (size_t)N * 64;
    hipMemsetAsync(aggs, 0, (size_t)N * 160 * 4, stream);
    k_msg<0><<<1536, 256, 0, stream>>>(s1, v1f, emb, sh0, sh1, eidx, Wm1, Wm2, W2s, W2v,
                                       nullptr, aggs, aggv, nullptr, nullptr);
    k_c1<<<1563, 256, 0, stream>>>(node_s, attrs, aggs, Wt0, BT, (float*)d_out, gts);
    k_c2<<<1563, 256, 0, stream>>>(node_v, attrs, aggv, Wt1, B2T, gts, (float*)d_out);
  }
}

// Round 5
// 852.564 us; speedup vs baseline: 1.9455x; 1.0627x over previous
//
#include <hip/hip_runtime.h>
#include <math.h>

#define N 50000
#define E 600000
#define EPB 16     // edges per pass
#define LDK 104    // padded K stride (bf16 elems) for tp tiles

typedef __attribute__((ext_vector_type(8))) short short8;
typedef __attribute__((ext_vector_type(4))) float float4v;

__device__ __forceinline__ float silu_f(float x) { return x / (1.f + __expf(-x)); }
__device__ __forceinline__ float sigm_f(float x) { return 1.f / (1.f + __expf(-x)); }
__device__ __forceinline__ unsigned short f2bf(float f) {
  unsigned u = __float_as_uint(f);
  u += 0x7fff + ((u >> 16) & 1);   // RNE
  return (unsigned short)(u >> 16);
}
__device__ __forceinline__ float bf2f(unsigned short u) {
  return __uint_as_float(((unsigned)u) << 16);
}

// ---------------- CSR build ----------------
__global__ void k_hist(const int* __restrict__ eidx, int* __restrict__ counts) {
  int e = blockIdx.x * 256 + threadIdx.x;
  if (e < E) atomicAdd(&counts[eidx[E + e]], 1);
}

__global__ __launch_bounds__(1024)
void k_scan(const int* __restrict__ counts, int* __restrict__ row_ptr) {
  __shared__ int ssum[1024];
  const int t = threadIdx.x;
  const int CH = 49;
  int lo = t * CH, hi = min(lo + CH, N);
  int s = 0;
  for (int i = lo; i < hi; i++) s += counts[i];
  ssum[t] = s;
  __syncthreads();
  for (int off = 1; off < 1024; off <<= 1) {
    int v = (t >= off) ? ssum[t - off] : 0;
    __syncthreads();
    ssum[t] += v;
    __syncthreads();
  }
  int run = (t == 0) ? 0 : ssum[t - 1];
  for (int i = lo; i < hi; i++) { row_ptr[i] = run; run += counts[i]; }
  if (t == 1023) row_ptr[N] = ssum[1023];
}

__global__ void k_scatter(const int* __restrict__ eidx, const int* __restrict__ row_ptr,
                          int* __restrict__ woff, int* __restrict__ perm) {
  int e = blockIdx.x * 256 + threadIdx.x;
  if (e < E) {
    int d = eidx[E + e];
    int p = atomicAdd(&woff[d], 1);
    perm[row_ptr[d] + p] = e;
  }
}

// ---------------- weight prep: bf16 transposed B matrices for k_c1/k_c2 ----------------
__global__ void k_prep(const float* __restrict__ Wsc0, const float* __restrict__ W3s,
                       const float* __restrict__ Wsc1, const float* __restrict__ W3v,
                       unsigned short* __restrict__ BT, unsigned short* __restrict__ B2T) {
  int i = blockIdx.x * 256 + threadIdx.x;
  if (i < 96 * 1088) {
    int j = i / 1088, k = i % 1088;
    float v;
    if (k < 1024) v = Wsc0[(size_t)k * 96 + j] * 0.03125f;          // 1/sqrt(1024)
    else          v = W3s[(size_t)(k - 1024) * 96 + j] * 0.125f;    // 1/sqrt(64)
    BT[i] = f2bf(v);
  } else {
    int i2 = i - 96 * 1088;
    if (i2 < 32 * 576) {
      int w = i2 / 576, k = i2 % 576;
      float v = 0.f;
      if (k < 512)      v = Wsc1[(size_t)k * 32 + w] * 0.04419417382415922f;  // 1/sqrt(512)
      else if (k < 544) v = W3v[(size_t)(k - 512) * 32 + w] * 0.17677669529663689f; // 1/sqrt(32)
      B2T[i2] = f2bf(v);
    }
  }
}

// ---------------- Kernel A: s1 = node_s@W1s/8 ; v1 = node_v x W1v /sqrt(32) ----------------
__global__ __launch_bounds__(256, 4)
void k_lin1(const float* __restrict__ node_s, const float* __restrict__ node_v,
            const float* __restrict__ W1s, const float* __restrict__ W1v,
            float* __restrict__ s1, float* __restrict__ v1) {
  __shared__ float w1s[64 * 64];
  __shared__ float w1v[32 * 32];
  for (int i = threadIdx.x; i < 64 * 64; i += 256) w1s[i] = W1s[i];
  for (int i = threadIdx.x; i < 32 * 32; i += 256) w1v[i] = W1v[i];
  __syncthreads();
  const float is_ns = 0.125f;
  const float is_nv = 0.17677669529663689f;
  int gtid = blockIdx.x * 256 + threadIdx.x;
  int stride = gridDim.x * 256;
  for (int i = gtid; i < N * 160; i += stride) {
    int n = i / 160, ch = i % 160;
    if (ch < 64) {
      const float* row = node_s + n * 64;
      float acc = 0.f;
#pragma unroll
      for (int u = 0; u < 64; u++) acc += row[u] * w1s[u * 64 + ch];
      s1[n * 64 + ch] = acc * is_ns;
    } else {
      int p = ch - 64, v = p / 3, c = p % 3;
      const float* row = node_v + n * 96;
      float acc = 0.f;
#pragma unroll
      for (int u = 0; u < 32; u++) acc += row[u * 3 + c] * w1v[u * 32 + v];
      v1[n * 96 + p] = acc * is_nv;
    }
  }
}

// ---------------- Kernel B: streaming per-edge message via MFMA ----------------
// STORE=1: coalesced bf16 messages in edge order (k_agg gathers via perm)
// STORE=0: fallback, atomicAdd into aggs/aggv
template<int STORE>
__global__ __launch_bounds__(256, 3)
void k_msg(const float* __restrict__ s1, const float* __restrict__ v1,
           const float* __restrict__ emb, const float* __restrict__ sh0g,
           const float* __restrict__ sh1g, const int* __restrict__ eidx,
           const float* __restrict__ Wm1, const float* __restrict__ Wm2,
           const float* __restrict__ W2s, const float* __restrict__ W2v,
           float* __restrict__ aggs, float* __restrict__ aggv,
           unsigned short* __restrict__ msgS, unsigned short* __restrict__ msgV) {
  __shared__ unsigned short w2sT[96 * LDK];   // W2sT[j][k] bf16 (isq96 folded)
  __shared__ unsigned short w2vT[32 * LDK];   // W2vT[v][k] bf16 (isq96 folded)
  __shared__ float wm2s[192 * 9];             // staging, stride 9 (bank-safe)
  __shared__ float wm1s[64];
  __shared__ unsigned short tps[EPB * LDK];
  __shared__ unsigned short tpv[EPB * 3 * LDK];
  __shared__ float gat[EPB][33];              // padded: bank-conflict-free
  __shared__ float hb[EPB][8];
  __shared__ float sh1b[EPB][4];
  __shared__ float sh0b[EPB];
  __shared__ int ssrc[EPB];
  __shared__ int sdst[EPB];

  const int t = threadIdx.x;
  const int wave = t >> 6, lane = t & 63;
  const int lm = lane & 15, quad = lane >> 4;
  const float isq96 = 0.10206207261596575f;

  // ---- one-time staging ----
  for (int i = t; i < 96 * 96; i += 256) {
    int k = i / 96, j = i % 96;
    w2sT[j * LDK + k] = f2bf(W2s[i] * isq96);
  }
  for (int i = t; i < 96 * 32; i += 256) {
    int u = i / 32, v = i % 32;
    w2vT[v * LDK + u] = f2bf(W2v[i] * isq96);
  }
  for (int i = t; i < 192 * 8; i += 256) {
    int h = i / 192, c = i % 192;
    wm2s[c * 9 + h] = Wm2[i];
  }
  if (t < 64) wm1s[t] = Wm1[t];
  __syncthreads();
  // register-cache this thread's 12 Wm2 rows (fixed by sub across all passes)
  const int subc = t & 15;
  float wA0[4][8], wA1[4][8], wB1[2][8], wB0[2][8];
#pragma unroll
  for (int i = 0; i < 4; i++)
#pragma unroll
    for (int h = 0; h < 8; h++) {
      wA0[i][h] = wm2s[(subc * 4 + i) * 9 + h];
      wA1[i][h] = wm2s[(64 + subc * 4 + i) * 9 + h];
    }
#pragma unroll
  for (int i2 = 0; i2 < 2; i2++)
#pragma unroll
    for (int h = 0; h < 8; h++) {
      wB1[i2][h] = wm2s[(128 + subc * 2 + i2) * 9 + h];
      wB0[i2][h] = wm2s[(160 + subc * 2 + i2) * 9 + h];
    }

  for (int pass = blockIdx.x; pass < E / EPB; pass += gridDim.x) {
    const int ebase = pass * EPB;
    __syncthreads();
    // ---- phase A: stage edge meta + radial MLP hidden (disjoint threads) ----
    if (t < EPB) {
      ssrc[t] = eidx[ebase + t];
      if (!STORE) sdst[t] = eidx[E + ebase + t];
      sh0b[t] = sh0g[ebase + t];
    } else if (t >= 64 && t < 64 + EPB * 3) {
      int i = t - 64;
      sh1b[i / 3][i % 3] = sh1g[ebase * 3 + i];
    } else if (t >= 128) {
      int i = t - 128, el = i >> 3, sub = i & 7;
      float acc = 0.f;
#pragma unroll
      for (int r = 0; r < 8; r++) acc += emb[(ebase + el) * 8 + r] * wm1s[r * 8 + sub];
      hb[el][sub] = silu_f(acc);
    }
    __syncthreads();
    // ---- phase B: build TPS / TPV (bf16), weights all in registers ----
    {
      const int el = t >> 4, sub = subc;
      const int src = ssrc[el];
      const float s0v = sh0b[el];
      const float x0 = sh1b[el][0], x1 = sh1b[el][1], x2 = sh1b[el][2];
      float hr[8];
#pragma unroll
      for (int h = 0; h < 8; h++) hr[h] = hb[el][h];
      const float4v ss = *(const float4v*)&s1[(size_t)src * 64 + sub * 4];
      unsigned short tsv[4], tvv[3][4];
#pragma unroll
      for (int i = 0; i < 4; i++) {
        float w0a = 0.f, w1a = 0.f;
#pragma unroll
        for (int h = 0; h < 8; h++) {
          w0a += hr[h] * wA0[i][h];
          w1a += hr[h] * wA1[i][h];
        }
        const float ssu = ss[i];
        tsv[i] = f2bf(w0a * ssu * s0v);
        const float base = w1a * ssu;
        tvv[0][i] = f2bf(base * x0);
        tvv[1][i] = f2bf(base * x1);
        tvv[2][i] = f2bf(base * x2);
      }
      *(uint2*)&tps[el * LDK + sub * 4] = *(uint2*)tsv;
#pragma unroll
      for (int c = 0; c < 3; c++)
        *(uint2*)&tpv[(el * 3 + c) * LDK + sub * 4] = *(uint2*)tvv[c];
      const float2* vp = (const float2*)&v1[(size_t)src * 96 + sub * 6];
      const float2 va = vp[0], vb = vp[1], vc = vp[2];
      const float v6[6] = {va.x, va.y, vb.x, vb.y, vc.x, vc.y};
      unsigned short ts2[2], tv2[3][2];
#pragma unroll
      for (int i2 = 0; i2 < 2; i2++) {
        float w1b = 0.f, w0b = 0.f;
#pragma unroll
        for (int h = 0; h < 8; h++) {
          w1b += hr[h] * wB1[i2][h];
          w0b += hr[h] * wB0[i2][h];
        }
        const float vx = v6[i2 * 3 + 0], vy = v6[i2 * 3 + 1], vz = v6[i2 * 3 + 2];
        ts2[i2] = f2bf(w0b * (vx * x0 + vy * x1 + vz * x2));
        tv2[0][i2] = f2bf(w1b * vx * s0v);
        tv2[1][i2] = f2bf(w1b * vy * s0v);
        tv2[2][i2] = f2bf(w1b * vz * s0v);
      }
      *(unsigned*)&tps[el * LDK + 64 + sub * 2] = *(unsigned*)ts2;
#pragma unroll
      for (int c = 0; c < 3; c++)
        *(unsigned*)&tpv[(el * 3 + c) * LDK + 64 + sub * 2] = *(unsigned*)tv2[c];
    }
    __syncthreads();
    // ---- GEMM1: m_s[16][96] ----
    {
      short8 afr[3];
#pragma unroll
      for (int kk = 0; kk < 3; kk++)
        afr[kk] = *(const short8*)&tps[lm * LDK + kk * 32 + quad * 8];
#pragma unroll
      for (int t2 = 0; t2 < 2; t2++) {
        const int nt = wave + t2 * 4;
        if (nt < 6) {
          float4v acc = {0.f, 0.f, 0.f, 0.f};
#pragma unroll
          for (int kk = 0; kk < 3; kk++) {
            short8 bfr = *(const short8*)&w2sT[(nt * 16 + lm) * LDK + kk * 32 + quad * 8];
            acc = __builtin_amdgcn_mfma_f32_16x16x32_bf16(afr[kk], bfr, acc, 0, 0, 0);
          }
          const int j = nt * 16 + lm;
#pragma unroll
          for (int reg = 0; reg < 4; reg++) {
            const int e = quad * 4 + reg;
            const float val = acc[reg];
            if (j < 64) {
              if (STORE) msgS[(size_t)(ebase + e) * 64 + j] = f2bf(silu_f(val));
              else atomicAdd(&aggs[(size_t)sdst[e] * 64 + j], silu_f(val));
            } else {
              gat[e][j - 64] = sigm_f(val);
            }
          }
        }
      }
    }
    __syncthreads();
    // ---- GEMM2: m_v[48][32] ----
#pragma unroll
    for (int t2 = 0; t2 < 2; t2++) {
      const int tile = wave + t2 * 4;
      if (tile < 6) {
        const int mt = tile >> 1, nt2 = tile & 1;
        float4v acc = {0.f, 0.f, 0.f, 0.f};
#pragma unroll
        for (int kk = 0; kk < 3; kk++) {
          short8 a = *(const short8*)&tpv[(mt * 16 + lm) * LDK + kk * 32 + quad * 8];
          short8 b = *(const short8*)&w2vT[(nt2 * 16 + lm) * LDK + kk * 32 + quad * 8];
          acc = __builtin_amdgcn_mfma_f32_16x16x32_bf16(a, b, acc, 0, 0, 0);
        }
        const int v = nt2 * 16 + lm;
#pragma unroll
        for (int reg = 0; reg < 4; reg++) {
          const int r = mt * 16 + quad * 4 + reg;
          const int e = (r * 171) >> 9, c = r - 3 * e;
          const float val = acc[reg] * gat[e][v];
          if (STORE) msgV[(size_t)(ebase + e) * 96 + v * 3 + c] = f2bf(val);
          else atomicAdd(&aggv[(size_t)sdst[e] * 96 + v * 3 + c], val);
        }
      }
    }
  }
}

// ---------------- Kernel B2: wave-per-node gather-reduction via perm ----------------
__global__ __launch_bounds__(256, 8)
void k_agg(const unsigned short* __restrict__ msgS, const unsigned short* __restrict__ msgV,
           const int* __restrict__ rowp, const int* __restrict__ perm,
           float* __restrict__ aggs, float* __restrict__ aggv) {
  const int wv = threadIdx.x >> 6, lane = threadIdx.x & 63;
  const int n = blockIdx.x * 4 + wv;
  const int lo = rowp[n], hi = rowp[n + 1];
  float sS = 0.f, v0 = 0.f, v1a = 0.f;
  int r = lo;
  for (; r + 2 <= hi; r += 2) {
    const int e0 = perm[r], e1 = perm[r + 1];
    const unsigned short a0 = msgS[(size_t)e0 * 64 + lane];
    const unsigned short a1 = msgS[(size_t)e1 * 64 + lane];
    const unsigned short b0 = msgV[(size_t)e0 * 96 + lane];
    const unsigned short b1 = msgV[(size_t)e1 * 96 + lane];
    unsigned short c0 = 0, c1 = 0;
    if (lane < 32) {
      c0 = msgV[(size_t)e0 * 96 + 64 + lane];
      c1 = msgV[(size_t)e1 * 96 + 64 + lane];
    }
    sS += bf2f(a0) + bf2f(a1);
    v0 += bf2f(b0) + bf2f(b1);
    v1a += bf2f(c0) + bf2f(c1);
  }
  for (; r < hi; r++) {
    const int e0 = perm[r];
    sS += bf2f(msgS[(size_t)e0 * 64 + lane]);
    v0 += bf2f(msgV[(size_t)e0 * 96 + lane]);
    if (lane < 32) v1a += bf2f(msgV[(size_t)e0 * 96 + 64 + lane]);
  }
  aggs[(size_t)n * 64 + lane] = sS;
  aggv[(size_t)n * 96 + lane] = v0;
  if (lane < 32) aggv[(size_t)n * 96 + 64 + lane] = v1a;
}

// ---------------- Kernel C1: MFMA GEMM  [32 nodes x 1088] @ BT^T -> 96 cols ----------------
__global__ __launch_bounds__(256, 4)
void k_c1(const float* __restrict__ node_s, const float* __restrict__ attrs,
          const float* __restrict__ aggs, const float* __restrict__ Wt0,
          const unsigned short* __restrict__ BT,
          float* __restrict__ out, float* __restrict__ gates) {
  __shared__ float s_row[32][64];
  __shared__ float attr[32][16];
  __shared__ float t0[32][64];
  __shared__ float wt0[1024];
  __shared__ unsigned short As[32 * 72];
  const int t = threadIdx.x;
  const int wave = t >> 6, lane = t & 63, lm = lane & 15, quad = lane >> 4;
  const int nbase = blockIdx.x * 32;

  for (int i = t; i < 1024; i += 256) wt0[i] = Wt0[i];
  for (int i = t; i < 2048; i += 256) {
    int nl = i >> 6, u = i & 63, n = nbase + nl;
    s_row[nl][u] = (n < N) ? node_s[(size_t)n * 64 + u] : 0.f;
    t0[nl][u]    = (n < N) ? aggs[(size_t)n * 64 + u] : 0.f;
  }
  for (int i = t; i < 512; i += 256) {
    int nl = i >> 4, a = i & 15, n = nbase + nl;
    attr[nl][a] = (n < N) ? attrs[(size_t)n * 16 + a] : 0.f;
  }
  __syncthreads();
  for (int i = t; i < 2048; i += 256) {
    int nl = i >> 6, u = i & 63;
    float d0 = 0.f;
#pragma unroll
    for (int a = 0; a < 16; a++) d0 += attr[nl][a] * wt0[u * 16 + a];
    t0[nl][u] *= d0 * 0.07216878364870322f;   // 1/(sqrt(16)*sqrt(12))
  }

  float4v acc[3] = {{0,0,0,0},{0,0,0,0},{0,0,0,0}};
  int mts[3], nts[3];
#pragma unroll
  for (int tt = 0; tt < 3; tt++) {
    const int tile = wave + tt * 4;    // 0..11 = mt*6+nt
    mts[tt] = tile / 6;
    nts[tt] = tile % 6;
  }

  for (int kc = 0; kc < 17; kc++) {
    __syncthreads();
    {
      const int row = t >> 3, c0 = (t & 7) * 8;
      unsigned short tmp[8];
      if (kc < 16) {
        const int u = kc * 4 + (c0 >> 4);
        const float sval = s_row[row][u];
        const int ab = c0 & 8;
#pragma unroll
        for (int i = 0; i < 8; i++) tmp[i] = f2bf(sval * attr[row][ab + i]);
      } else {
#pragma unroll
        for (int i = 0; i < 8; i++) tmp[i] = f2bf(t0[row][c0 + i]);
      }
      *(uint4*)&As[row * 72 + c0] = *(uint4*)tmp;
    }
    __syncthreads();
#pragma unroll
    for (int ks = 0; ks < 2; ks++) {
      short8 am0 = *(const short8*)&As[(lm) * 72 + ks * 32 + quad * 8];
      short8 am1 = *(const short8*)&As[(16 + lm) * 72 + ks * 32 + quad * 8];
#pragma unroll
      for (int tt = 0; tt < 3; tt++) {
        short8 b = *(const short8*)&BT[(size_t)(nts[tt] * 16 + lm) * 1088 + kc * 64 + ks * 32 + quad * 8];
        acc[tt] = __builtin_amdgcn_mfma_f32_16x16x32_bf16(mts[tt] ? am1 : am0, b, acc[tt], 0, 0, 0);
      }
    }
  }
#pragma unroll
  for (int tt = 0; tt < 3; tt++) {
    const int j = nts[tt] * 16 + lm;
#pragma unroll
    for (int reg = 0; reg < 4; reg++) {
      const int m = mts[tt] * 16 + quad * 4 + reg;
      const int n = nbase + m;
      if (n < N) {
        const float val = acc[tt][reg];
        if (j < 64) out[(size_t)n * 160 + j] = silu_f(val);
        else        gates[(size_t)n * 32 + (j - 64)] = sigm_f(val);
      }
    }
  }
}

// ---------------- Kernel C2: MFMA GEMM  [96 rows (32n x 3c) x 544] @ B2T^T -> 32 cols ----------------
__global__ __launch_bounds__(256, 3)
void k_c2(const float* __restrict__ node_v, const float* __restrict__ attrs,
          const float* __restrict__ aggv, const float* __restrict__ Wt1,
          const unsigned short* __restrict__ B2T, const float* __restrict__ gts,
          float* __restrict__ out) {
  __shared__ float nvs[32][96];
  __shared__ float t1s[32][96];
  __shared__ float attr[32][16];
  __shared__ float wt1[512];
  __shared__ unsigned short As2[96 * 72];
  const int t = threadIdx.x;
  const int wave = t >> 6, lane = t & 63, lm = lane & 15, quad = lane >> 4;
  const int nbase = blockIdx.x * 32;

  for (int i = t; i < 512; i += 256) wt1[i] = Wt1[i];
  for (int i = t; i < 32 * 96; i += 256) {
    int nl = i / 96, rr = i % 96, n = nbase + nl;
    nvs[nl][rr] = (n < N) ? node_v[(size_t)n * 96 + rr] : 0.f;
    t1s[nl][rr] = (n < N) ? aggv[(size_t)n * 96 + rr] : 0.f;
  }
  for (int i = t; i < 512; i += 256) {
    int nl = i >> 4, a = i & 15, n = nbase + nl;
    attr[nl][a] = (n < N) ? attrs[(size_t)n * 16 + a] : 0.f;
  }
  __syncthreads();
  for (int i = t; i < 1024; i += 256) {
    int nl = i >> 5, u = i & 31;
    float d1 = 0.f;
#pragma unroll
    for (int a = 0; a < 16; a++) d1 += attr[nl][a] * wt1[u * 16 + a];
    d1 *= 0.07216878364870322f;
    t1s[nl][u * 3 + 0] *= d1; t1s[nl][u * 3 + 1] *= d1; t1s[nl][u * 3 + 2] *= d1;
  }

  float4v acc[3] = {{0,0,0,0},{0,0,0,0},{0,0,0,0}};
  int mts[3], nts[3];
#pragma unroll
  for (int tt = 0; tt < 3; tt++) {
    const int tile = wave + tt * 4;   // 0..11 = mt*2+nt
    mts[tt] = tile >> 1;
    nts[tt] = tile & 1;
  }

  for (int kc = 0; kc < 9; kc++) {
    __syncthreads();
#pragma unroll
    for (int jj = 0; jj < 3; jj++) {
      const int job = t + jj * 256;
      const int row = job >> 3, c0 = (job & 7) * 8;
      const int nl = (row * 171) >> 9, c = row - 3 * nl;
      const int kbase = kc * 64 + c0;
      unsigned short tmp[8];
      if (kbase < 512) {
        const int u = kbase >> 4;
        const float vval = nvs[nl][u * 3 + c];
        const int ab = c0 & 8;
#pragma unroll
        for (int i = 0; i < 8; i++) tmp[i] = f2bf(vval * attr[nl][ab + i]);
      } else if (kbase < 544) {
        const int u2 = kbase - 512;
#pragma unroll
        for (int i = 0; i < 8; i++) tmp[i] = f2bf(t1s[nl][(u2 + i) * 3 + c]);
      } else {
#pragma unroll
        for (int i = 0; i < 8; i++) tmp[i] = 0;
      }
      *(uint4*)&As2[row * 72 + c0] = *(uint4*)tmp;
    }
    __syncthreads();
#pragma unroll
    for (int ks = 0; ks < 2; ks++) {
#pragma unroll
      for (int tt = 0; tt < 3; tt++) {
        short8 a = *(const short8*)&As2[(mts[tt] * 16 + lm) * 72 + ks * 32 + quad * 8];
        short8 b = *(const short8*)&B2T[(size_t)(nts[tt] * 16 + lm) * 576 + kc * 64 + ks * 32 + quad * 8];
        acc[tt] = __builtin_amdgcn_mfma_f32_16x16x32_bf16(a, b, acc[tt], 0, 0, 0);
      }
    }
  }
#pragma unroll
  for (int tt = 0; tt < 3; tt++) {
    const int w = nts[tt] * 16 + lm;
#pragma unroll
    for (int reg = 0; reg < 4; reg++) {
      const int row = mts[tt] * 16 + quad * 4 + reg;
      const int nl = (row * 171) >> 9, c = row - 3 * nl;
      const int n = nbase + nl;
      if (n < N)
        out[(size_t)n * 160 + 64 + w * 3 + c] = acc[tt][reg] * gts[(size_t)n * 32 + w];
    }
  }
}

extern "C" void kernel_launch(void* const* d_in, const int* in_sizes, int n_in,
                              void* d_out, int out_size, void* d_ws, size_t ws_size,
                              hipStream_t stream) {
  const float* node_s = (const float*)d_in[0];
  const float* node_v = (const float*)d_in[1];
  const float* attrs  = (const float*)d_in[2];
  const float* emb    = (const float*)d_in[3];
  const float* sh0    = (const float*)d_in[4];
  const float* sh1    = (const float*)d_in[5];
  const int*   eidx   = (const int*)d_in[6];
  const float* W1s    = (const float*)d_in[7];
  const float* W1v    = (const float*)d_in[8];
  const float* Wm1    = (const float*)d_in[9];
  const float* Wm2    = (const float*)d_in[10];
  const float* W2s    = (const float*)d_in[11];
  const float* W2v    = (const float*)d_in[12];
  const float* Wt0    = (const float*)d_in[13];
  const float* Wt1    = (const float*)d_in[14];
  const float* W3s    = (const float*)d_in[15];
  const float* W3v    = (const float*)d_in[16];
  const float* Wsc0   = (const float*)d_in[17];
  const float* Wsc1   = (const float*)d_in[18];

  char* p = (char*)d_ws;
  float* s1  = (float*)p;  p += (size_t)N * 64 * 4;
  float* v1f = (float*)p;  p += (size_t)N * 96 * 4;
  float* gts = (float*)p;  p += (size_t)N * 32 * 4;
  unsigned short* BT  = (unsigned short*)p;  p += (size_t)96 * 1088 * 2;
  unsigned short* B2T = (unsigned short*)p;  p += (size_t)32 * 576 * 2;
  char* pmode = p;
  size_t base = (size_t)(pmode - (char*)d_ws);
  size_t need_store = base + ((size_t)N + 1) * 4 + (size_t)N * 4 + (size_t)E * 4
                    + (size_t)E * 64 * 2 + (size_t)E * 96 * 2;
  const bool store = (ws_size >= need_store);

  k_prep<<<480, 256, 0, stream>>>(Wsc0, W3s, Wsc1, W3v, BT, B2T);
  k_lin1<<<1024, 256, 0, stream>>>(node_s, node_v, W1s, W1v, s1, v1f);

  if (store) {
    int* rowp = (int*)pmode;
    int* cnt  = rowp + (N + 1);
    int* perm = cnt + N;
    unsigned short* msgS = (unsigned short*)(perm + E);
    unsigned short* msgV = msgS + (size_t)E * 64;
    hipMemsetAsync(cnt, 0, (size_t)N * 4, stream);
    k_hist<<<(E + 255) / 256, 256, 0, stream>>>(eidx, cnt);
    k_scan<<<1, 1024, 0, stream>>>(cnt, rowp);
    hipMemsetAsync(cnt, 0, (size_t)N * 4, stream);
    k_scatter<<<(E + 255) / 256, 256, 0, stream>>>(eidx, rowp, cnt, perm);
    k_msg<1><<<1536, 256, 0, stream>>>(s1, v1f, emb, sh0, sh1, eidx, Wm1, Wm2, W2s, W2v,
                                       nullptr, nullptr, msgS, msgV);
    float* aggs = s1;    // s1/v1 dead after k_msg: alias
    float* aggv = v1f;
    k_agg<<<N / 4, 256, 0, stream>>>(msgS, msgV, rowp, perm, aggs, aggv);
    k_c1<<<1563, 256, 0, stream>>>(node_s, attrs, aggs, Wt0, BT, (float*)d_out, gts);
    k_c2<<<1563, 256, 0, stream>>>(node_v, attrs, aggv, Wt1, B2T, gts, (float*)d_out);
  } else {
    float* aggs = (float*)pmode;
    float* aggv = aggs + (size_t)N * 64;
    hipMemsetAsync(aggs, 0, (size_t)N * 160 * 4, stream);
    k_msg<0><<<1536, 256, 0, stream>>>(s1, v1f, emb, sh0, sh1, eidx, Wm1, Wm2, W2s, W2v,
                                       aggs, aggv, nullptr, nullptr);
    k_c1<<<1563, 256, 0, stream>>>(node_s, attrs, aggs, Wt0, BT, (float*)d_out, gts);
    k_c2<<<1563, 256, 0, stream>>>(node_v, attrs, aggv, Wt1, B2T, gts, (float*)d_out);
  }
}